// Round 13
// baseline (3268.763 us; speedup 1.0000x reference)
//
#include <hip/hip_runtime.h>

// Residual VQ forward (eval): x [16,2048,256] f32, embeddings [8,1024,256] f32
// outputs concat: quantized [N*D], loss [1], codes [N*L] (as float)
// N = 32768, D = 256, L = 8, K = 1024.
//
// R9 = R8 with the j-loop FULLY unrolled (rule #20: partial unroll left
// acc[8][16] runtime-indexed -> scratch). d-slice-outer (4 floats) x
// all-K-inner, acc[8][16] per thread held across the layer; 28 LDS b128 ops
// per 512 FMA (R7 was 52 -> LDS-issue-bound at VALUBusy 44%).
// Es = float4[2][1024] double-buffered slice (32KB); 70.3KB LDS, 2 blocks/CU.

#define NL 8
#define NK 1024
#define ND 256
#define NROWTOT 32768
#define ROWS 32
#define RSTR 260    // 256+4 floats: 65 f4-slots/row == 1 mod 8 -> conflict-free epilogue

// ---------------------------------------------------------------- prologue ---
__global__ __launch_bounds__(256)
void enorm_zero_kernel(const float* __restrict__ emb, float* __restrict__ enorm,
                       float* __restrict__ loss_slot) {
    // 8192 codebook rows, 256 blocks x 32 rows, 8 lanes per row
    int row = blockIdx.x * 32 + (threadIdx.x >> 3);
    int l8  = threadIdx.x & 7;
    const float4* e4 = (const float4*)(emb + (size_t)row * ND);
    float s = 0.f;
#pragma unroll
    for (int q = 0; q < 8; ++q) {
        float4 v = e4[q * 8 + l8];
        s = fmaf(v.x, v.x, s); s = fmaf(v.y, v.y, s);
        s = fmaf(v.z, v.z, s); s = fmaf(v.w, v.w, s);
    }
    s += __shfl_xor(s, 1);
    s += __shfl_xor(s, 2);
    s += __shfl_xor(s, 4);
    if (l8 == 0) enorm[row] = s;
    if (blockIdx.x == 0 && threadIdx.x == 0) *loss_slot = 0.f;  // d_out poisoned 0xAA
}

// -------------------------------------------------------------------- main ---
__global__ __launch_bounds__(256, 2)
void rvq_kernel(const float* __restrict__ x, const float* __restrict__ emb,
                const float* __restrict__ enorm, float* __restrict__ out) {
    __shared__ float  R[ROWS][RSTR];   // 33280 B residual tile
    __shared__ float4 Es[2][NK];       // 32768 B dbuf codebook d-slice (4 floats/k)
    __shared__ float  En[NK];          //  4096 B ||e||^2 for current layer
    __shared__ int    amin[ROWS];
    __shared__ float  lred[4];

    const int tid   = threadIdx.x;
    const int tx    = tid & 63;        // k lane (whole wave)
    const int ty    = tid >> 6;        // wave id = row group (rows ty*8..ty*8+7)
    const int row_e = tid >> 3;        // epilogue row 0..31
    const int dq    = tid & 7;         // epilogue lane-in-row
    const int brow  = blockIdx.x * ROWS;

    float* loss_slot = out + (size_t)NROWTOT * ND;
    float* codes     = loss_slot + 1;

    // load x tile into LDS residual
    const float4* x4 = (const float4*)(x + (size_t)(brow + row_e) * ND);
#pragma unroll
    for (int q = 0; q < 8; ++q) {
        int qq = q * 8 + dq;
        *(float4*)&R[row_e][qq * 4] = x4[qq];
    }

    // slice g (0..511): l = g>>6, dc = g&63.  Slice g lives in Es[g&1];
    // stage regs hold slice g+1.  Staged data: emb[l][k][dc*4 .. dc*4+3],
    // thread t covers rows k = t + 256p, p = 0..3.
    const float4* emb4 = (const float4*)emb;   // row stride 64 f4, layer 65536 f4
    float4 stage[4];
    // slice 0 -> Es[0]
#pragma unroll
    for (int p = 0; p < 4; ++p)
        stage[p] = emb4[(size_t)(tid + 256 * p) * 64];
#pragma unroll
    for (int p = 0; p < 4; ++p)
        Es[0][tid + 256 * p] = stage[p];
    // prefetch slice 1 (l=0, dc=1)
#pragma unroll
    for (int p = 0; p < 4; ++p)
        stage[p] = emb4[(size_t)(tid + 256 * p) * 64 + 1];

    float loss_acc = 0.f;

    for (int l = 0; l < NL; ++l) {
        // stage ||e||^2 (first read after the dc loop; ordered by barriers)
        const float* enl = enorm + l * NK;
#pragma unroll
        for (int p = 0; p < 4; ++p) En[tid + p * 256] = enl[tid + p * 256];

        float acc[8][16];
#pragma unroll
        for (int i = 0; i < 8; ++i)
#pragma unroll
            for (int j = 0; j < 16; ++j) acc[i][j] = 0.f;

        for (int dc = 0; dc < 64; ++dc) {
            const int g   = l * 64 + dc;         // global slice
            const int buf = g & 1;

            __syncthreads();  // readers of Es[buf^1] (slice g-1) done; at layer
                              // start also orders epilogue/prologue R writes
            // commit prefetched slice g+1 -> Es[buf^1]
#pragma unroll
            for (int p = 0; p < 4; ++p)
                Es[buf ^ 1][tid + 256 * p] = stage[p];
            // issue prefetch of slice g+2 (consumed at next slice top)
            {
                int gp = g + 2; if (gp > 511) gp = 511;
                const int lp = gp >> 6, dcp = gp & 63;
                const size_t base = (size_t)lp * 65536 + (size_t)tid * 64 + dcp;
#pragma unroll
                for (int p = 0; p < 4; ++p)
                    stage[p] = emb4[base + (size_t)(p * 256) * 64];
            }
            // rv: this wave's 8 rows, d-slice dc (wave-uniform -> broadcast)
            float4 rv[8];
#pragma unroll
            for (int i = 0; i < 8; ++i)
                rv[i] = *(const float4*)&R[ty * 8 + i][dc * 4];
            // FMA over all K: acc[i][j] += R[row][d] * E[k = j*64+tx][d]
            // FULL unroll: every acc index compile-time (rule #20)
#pragma unroll
            for (int j = 0; j < 16; ++j) {
                float4 ev = Es[buf][j * 64 + tx];
#pragma unroll
                for (int i = 0; i < 8; ++i) {
                    acc[i][j] = fmaf(rv[i].x, ev.x, acc[i][j]);
                    acc[i][j] = fmaf(rv[i].y, ev.y, acc[i][j]);
                    acc[i][j] = fmaf(rv[i].z, ev.z, acc[i][j]);
                    acc[i][j] = fmaf(rv[i].w, ev.w, acc[i][j]);
                }
            }
        }
        // fold distances into per-thread argmin (j ascending == k ascending)
        float minv[8];
        int   mini[8];
#pragma unroll
        for (int i = 0; i < 8; ++i) { minv[i] = 3.4e38f; mini[i] = 0; }
#pragma unroll
        for (int j = 0; j < 16; ++j) {
            int   kg = j * 64 + tx;
            float en = En[kg];
#pragma unroll
            for (int i = 0; i < 8; ++i) {
                float dv = fmaf(-2.f, acc[i][j], en);
                if (dv < minv[i]) { minv[i] = dv; mini[i] = kg; }
            }
        }
        // cross-lane argmin over the wave (ties -> smaller index)
#pragma unroll
        for (int off = 32; off >= 1; off >>= 1) {
#pragma unroll
            for (int i = 0; i < 8; ++i) {
                float ov = __shfl_xor(minv[i], off);
                int   oi = __shfl_xor(mini[i], off);
                if (ov < minv[i] || (ov == minv[i] && oi < mini[i])) {
                    minv[i] = ov; mini[i] = oi;
                }
            }
        }
        if (tx == 0) {
#pragma unroll
            for (int i = 0; i < 8; ++i) amin[ty * 8 + i] = mini[i];
        }
        __syncthreads();
        // epilogue: gather q, loss, STE residual update (reference op-order)
        {
            const float* el = emb + (size_t)l * NK * ND;
            int idx = amin[row_e];
            const float4* q4 = (const float4*)(el + (size_t)idx * ND);
#pragma unroll
            for (int q = 0; q < 8; ++q) {
                int qq = q * 8 + dq;
                float4 qv = q4[qq];
                float4 rv = *(const float4*)&R[row_e][qq * 4];
                float4 df, qs, rn;
                df.x = qv.x - rv.x; df.y = qv.y - rv.y;
                df.z = qv.z - rv.z; df.w = qv.w - rv.w;
                loss_acc = fmaf(df.x, df.x, loss_acc);
                loss_acc = fmaf(df.y, df.y, loss_acc);
                loss_acc = fmaf(df.z, df.z, loss_acc);
                loss_acc = fmaf(df.w, df.w, loss_acc);
                qs.x = rv.x + df.x; qs.y = rv.y + df.y;   // q_st = r + (q - r)
                qs.z = rv.z + df.z; qs.w = rv.w + df.w;
                rn.x = rv.x - qs.x; rn.y = rv.y - qs.y;   // r = r - q_st
                rn.z = rv.z - qs.z; rn.w = rv.w - qs.w;
                *(float4*)&R[row_e][qq * 4] = rn;
            }
            if (dq == 0) codes[(size_t)(brow + row_e) * NL + l] = (float)idx;
        }
        // next slice's top __syncthreads() orders R writes vs reads
    }
    // quantized_out = x - residual_final (telescoped sum of q_st)
#pragma unroll
    for (int q = 0; q < 8; ++q) {
        int qq = q * 8 + dq;
        float4 xv = x4[qq];
        float4 rv = *(const float4*)&R[row_e][qq * 4];
        float4 ov;
        ov.x = xv.x - rv.x; ov.y = xv.y - rv.y;
        ov.z = xv.z - rv.z; ov.w = xv.w - rv.w;
        ((float4*)(out + (size_t)(brow + row_e) * ND))[qq] = ov;
    }
    // loss: wave reduce, per-wave partials, one atomic per block
#pragma unroll
    for (int off = 32; off >= 1; off >>= 1) loss_acc += __shfl_xor(loss_acc, off);
    if ((tid & 63) == 0) lred[tid >> 6] = loss_acc;
    __syncthreads();
    if (tid == 0) {
        float t = lred[0] + lred[1] + lred[2] + lred[3];
        atomicAdd(loss_slot, t * (0.25f / ((float)NROWTOT * (float)ND)));
    }
}

// ------------------------------------------------------------------ launch ---
extern "C" void kernel_launch(void* const* d_in, const int* in_sizes, int n_in,
                              void* d_out, int out_size, void* d_ws, size_t ws_size,
                              hipStream_t stream) {
    const float* x   = (const float*)d_in[0];   // [32768, 256]
    const float* emb = (const float*)d_in[1];   // [8, 1024, 256]
    float* out   = (float*)d_out;
    float* enorm = (float*)d_ws;                // [8192] floats
    float* loss_slot = out + (size_t)NROWTOT * ND;

    enorm_zero_kernel<<<256, 256, 0, stream>>>(emb, enorm, loss_slot);
    rvq_kernel<<<NROWTOT / ROWS, 256, 0, stream>>>(x, emb, enorm, out);
}